// Round 8
// baseline (77.678 us; speedup 1.0000x reference)
//
#include <hip/hip_runtime.h>
#include <hip/hip_bf16.h>

typedef __bf16 bf16x8 __attribute__((ext_vector_type(8)));
typedef float  f32x4  __attribute__((ext_vector_type(4)));

#define MFMA(a, b, c) __builtin_amdgcn_mfma_f32_16x16x32_bf16((a), (b), (c), 0, 0, 0)

// R8: barrier-free m-split. R2/R6/R7 showed the barrier'd producer-consumer
// structure pins us at ~74-77us regardless of pipelining/occupancy tweaks.
// Here each wave owns 16 edges end-to-end:
//  - x: global -> registers directly as A-fragments (lane lc reads its own
//    row's contiguous 32B k-chunk). No XH staging, no cross-wave sharing,
//    HBM traffic still exactly-once (each row read by exactly one wave).
//  - w1 B-frags staged ONCE to LDS (16KB, lane-linear -> conflict-free
//    ds_read_b128); the R3 register blowup avoided.
//  - H: acc -> relu -> wave-private HF slice (4KB/wave) -> A-frag reads.
//    Same-wave DS ops execute in order; asm memory fences stop compiler
//    reordering. ZERO __syncthreads in the main loop -> 12 independent
//    waves/CU, pure TLP latency hiding, no lockstep.
//  - Precision: x/w1/wp hi-only bf16, w2 split hi/lo (absmax pinned at 2^-8
//    across all precision variants R1-R7).
// LDS 32KB (W1F 16K + HF 4x4K); VGPR est ~130 -> 3 blocks/CU at (256,3).

__device__ __forceinline__ int swz(int row, int byteInRow) {
    return row * 256 + (byteInRow ^ ((row & 7) << 4));
}

__global__ __launch_bounds__(256, 3) void edge_moe_kernel(
    const float* __restrict__ x,  const float* __restrict__ w1,
    const float* __restrict__ b1, const float* __restrict__ w2,
    const float* __restrict__ b2, const float* __restrict__ wp,
    float* __restrict__ outFused, float* __restrict__ outAlpha, int E)
{
    __shared__ __align__(16) char lds[32768];
    char* W1F = lds;               // [combo=kk*4+nt][lane] bf16x8 : 16*64*16B = 16KB
    char* HFB = lds + 16384;       // 4 waves x 4KB wave-private [16][64] f32, swz

    const int tid  = threadIdx.x;
    const int lane = tid & 63;
    const int wid  = tid >> 6;
    const int lc   = lane & 15;
    const int lg   = lane >> 4;
    char* HFW = HFB + wid * 4096;

    // ---- Stage w1 B-fragments to LDS (hi-only), wave w covers combos 4w..4w+3 ----
    // B-frag (16x16x32): lane holds B[k = kk*32 + lg*8 + j][n = nt*16 + lc].
#pragma unroll
    for (int i = 0; i < 4; ++i) {
        int combo = wid * 4 + i;
        int kk = combo >> 2, nt = combo & 3;
        bf16x8 h;
#pragma unroll
        for (int j = 0; j < 8; ++j) {
            int kidx = kk * 32 + lg * 8 + j;
            h[j] = (__bf16)w1[kidx * 64 + nt * 16 + lc];
        }
        *(bf16x8*)(W1F + combo * 1024 + lane * 16) = h;
    }

    // ---- w2 (split hi/lo) and wp (hi) B-fragments in registers ----
    bf16x8 w2h[2], w2l[2];
#pragma unroll
    for (int kk = 0; kk < 2; ++kk) {
        bf16x8 h, l;
#pragma unroll
        for (int j = 0; j < 8; ++j) {
            int kidx = kk * 32 + lg * 8 + j;
            float v = (lc < 8) ? w2[kidx * 8 + lc] : 0.0f;
            __bf16 hb = (__bf16)v;
            h[j] = hb; l[j] = (__bf16)(v - (float)hb);
        }
        w2h[kk] = h; w2l[kk] = l;
    }
    bf16x8 wph[4];
#pragma unroll
    for (int kk = 0; kk < 4; ++kk) {
        bf16x8 h;
#pragma unroll
        for (int j = 0; j < 8; ++j) {
            int kidx = kk * 32 + lg * 8 + j;
            h[j] = (lc < 8) ? (__bf16)wp[kidx * 8 + lc] : (__bf16)0.0f;
        }
        wph[kk] = h;
    }
    float b1v[4];
#pragma unroll
    for (int nt = 0; nt < 4; ++nt) b1v[nt] = b1[nt * 16 + lc];
    const float b2v = (lc < 8) ? b2[lc] : 0.0f;

    __syncthreads();   // the ONLY barrier: W1F staged and visible

    const int ntiles = (E + 63) >> 6;

    for (int tile = blockIdx.x; tile < ntiles; tile += gridDim.x) {
        const long long eb = (long long)tile * 64;

        // ---- Load this lane's A-row directly from global (32B chunks x 4kk) ----
        long long e = eb + wid * 16 + lc;
        if (e > (long long)E - 1) e = (long long)E - 1;
        const float* xr = x + (size_t)e * 128;

        bf16x8 axh[4];
#pragma unroll
        for (int kk = 0; kk < 4; ++kk) {
            const f32x4* p = (const f32x4*)(xr + kk * 32 + lg * 8);
            f32x4 x0 = p[0];
            f32x4 x1 = p[1];
            bf16x8 a;
#pragma unroll
            for (int j = 0; j < 4; ++j) {
                a[j]     = (__bf16)x0[j];
                a[j + 4] = (__bf16)x1[j];
            }
            axh[kk] = a;
        }

        // ---- H = relu(x @ w1 + b1): 16 MFMA, B-frags from LDS (conflict-free) ----
        f32x4 acc[4] = {{0.f,0.f,0.f,0.f},{0.f,0.f,0.f,0.f},{0.f,0.f,0.f,0.f},{0.f,0.f,0.f,0.f}};
#pragma unroll
        for (int kk = 0; kk < 4; ++kk)
#pragma unroll
            for (int nt = 0; nt < 4; ++nt) {
                bf16x8 wf = *(const bf16x8*)(W1F + (kk * 4 + nt) * 1024 + lane * 16);
                acc[nt] = MFMA(axh[kk], wf, acc[nt]);
            }

        // ---- relu+bias -> wave-private HF (C-layout row = lg*4+r, col = nt*16+lc) ----
#pragma unroll
        for (int nt = 0; nt < 4; ++nt)
#pragma unroll
            for (int r = 0; r < 4; ++r) {
                float hv = fmaxf(acc[nt][r] + b1v[nt], 0.f);
                *(float*)(HFW + swz(lg * 4 + r, (nt * 16 + lc) * 4)) = hv;
            }
        asm volatile("" ::: "memory");   // keep HF writes before HF reads (same-wave
                                         // DS ops execute in order on HW)

        // ---- logits = H@w2 + b2 (H->bf16 once, w2 split); scores = x@wp (axh) ----
        f32x4 lac = {0.f, 0.f, 0.f, 0.f};
        f32x4 sac = {0.f, 0.f, 0.f, 0.f};
#pragma unroll
        for (int kk = 0; kk < 2; ++kk) {
            int base = kk * 128 + lg * 32;     // f32 bytes: k = kk*32 + lg*8
            f32x4 h0 = *(const f32x4*)(HFW + swz(lc, base));
            f32x4 h1 = *(const f32x4*)(HFW + swz(lc, base + 16));
            bf16x8 hh;
#pragma unroll
            for (int j = 0; j < 4; ++j) {
                hh[j]     = (__bf16)h0[j];
                hh[j + 4] = (__bf16)h1[j];
            }
            lac = MFMA(hh, w2h[kk], lac);
            lac = MFMA(hh, w2l[kk], lac);
        }
#pragma unroll
        for (int kk = 0; kk < 4; ++kk) {
            sac = MFMA(axh[kk], wph[kk], sac);
        }
        asm volatile("" ::: "memory");   // keep this iter's HF reads before next
                                         // iter's HF writes

        // ---- Softmax over 8 cols (lanes lc<8; no max-sub) + fused dot ----
#pragma unroll
        for (int r = 0; r < 4; ++r) {
            float lv = lac[r] + b2v;           // TEMPERATURE = 1.0
            float p = __expf(lv);
            float s  = p;
            float fs = p * sac[r];
            s  += __shfl_xor(s, 1);  fs += __shfl_xor(fs, 1);
            s  += __shfl_xor(s, 2);  fs += __shfl_xor(fs, 2);
            s  += __shfl_xor(s, 4);  fs += __shfl_xor(fs, 4);
            float inv = 1.0f / s;
            float alpha = p * inv;
            float fv = fs * inv;
            long long edge = eb + wid * 16 + lg * 4 + r;
            if (edge < E) {
                if (lc < 8) outAlpha[edge * 8 + lc] = alpha;
                if (lc == 0) outFused[edge] = fv;
            }
        }
        // no barrier: next iteration is fully wave-local
    }
}

extern "C" void kernel_launch(void* const* d_in, const int* in_sizes, int n_in,
                              void* d_out, int out_size, void* d_ws, size_t ws_size,
                              hipStream_t stream) {
    const float* x  = (const float*)d_in[0];
    const float* w1 = (const float*)d_in[1];
    const float* b1 = (const float*)d_in[2];
    const float* w2 = (const float*)d_in[3];
    const float* b2 = (const float*)d_in[4];
    const float* wp = (const float*)d_in[5];

    const int E = in_sizes[0] / 128;
    float* outF = (float*)d_out;
    float* outA = outF + E;

    const int ntiles = (E + 63) >> 6;
    const int blocks = ntiles < 1024 ? ntiles : 1024;
    edge_moe_kernel<<<blocks, 256, 0, stream>>>(x, w1, b1, w2, b2, wp, outF, outA, E);
}